// Round 9
// baseline (131.301 us; speedup 1.0000x reference)
//
#include <hip/hip_runtime.h>

// Problem constants
#define B_SZ   8
#define S_LEN  1024
#define D_MOD  256
#define NHEADS 8
#define LOG2E  1.4426950408889634f
#define QSCALE_LOG2E 0.2550352766751165f   // (1/sqrt(32)) * log2(e)

typedef _Float16 f16x8 __attribute__((ext_vector_type(8)));
typedef _Float16 f16x4 __attribute__((ext_vector_type(4)));
typedef float    f32x4 __attribute__((ext_vector_type(4)));

// ---------------------------------------------------------------------------
// prep: blocks 0..31  : pack 4 fp32 W mats -> fragment-ordered fp16 wtp.
//        wtp[((mat*16+n16)*8+kk)*512 + lane*8 + j]
//          = W[kk*32 + (lane>>4)*8 + j][n16*16 + (lane&15)]
//       blocks 32..94 : fp16 bias C-init table
//        tabh[((h*63+dy31)*3+e)*256 + lane*4 + r]
//          = rel[(dy31*63 + 16e + l16 - quad*4 - r + 15)*8 + h] * LOG2E
// ---------------------------------------------------------------------------
__global__ __launch_bounds__(256)
void prep_kernel(const float* __restrict__ Wq, const float* __restrict__ Wk,
                 const float* __restrict__ Wv, const float* __restrict__ Wo,
                 const float* __restrict__ rel,
                 _Float16* __restrict__ wtp, _Float16* __restrict__ tabh) {
    if (blockIdx.x < 32) {
        __shared__ _Float16 Wl[32 * 264];
        const int mi = blockIdx.x >> 3;
        const int k0 = (blockIdx.x & 7) << 5;
        const float* W = (mi == 0) ? Wq : (mi == 1) ? Wk : (mi == 2) ? Wv : Wo;
        {
            const int r  = threadIdx.x >> 3;
            const int c4 = (threadIdx.x & 7) * 4;
            const float* src = W + (size_t)(k0 + r) * 256 + c4;
#pragma unroll
            for (int g = 0; g < 8; ++g) {
                f32x4 v = *(const f32x4*)(src + g * 32);
                f16x4 o;
#pragma unroll
                for (int j = 0; j < 4; ++j) o[j] = (_Float16)v[j];
                *(f16x4*)(&Wl[r * 264 + c4 + g * 32]) = o;
            }
        }
        __syncthreads();
        const int n16 = threadIdx.x >> 4;
        const int l16 = threadIdx.x & 15;
        const int kk  = k0 >> 5;
#pragma unroll
        for (int quad = 0; quad < 4; ++quad) {
            f16x8 v;
#pragma unroll
            for (int j = 0; j < 8; ++j) v[j] = Wl[(quad * 8 + j) * 264 + n16 * 16 + l16];
            *(f16x8*)(wtp + (((size_t)(mi * 16 + n16) * 8 + kk) << 9) + (quad * 16 + l16) * 8) = v;
        }
        return;
    }
    __shared__ float rl[63 * 8];
    const int dy31 = blockIdx.x - 32;
    for (int f = threadIdx.x; f < 504; f += 256) rl[f] = rel[(size_t)dy31 * 504 + f];
    __syncthreads();
    const int h  = threadIdx.x >> 5;
    const int r5 = threadIdx.x & 31;
#pragma unroll
    for (int c = 0; c < 6; ++c) {
        const int oi   = r5 * 6 + c;       // 0..191
        const int e    = oi >> 6;
        const int lane = oi & 63;
        const int quad = lane >> 4, l16 = lane & 15;
        f16x4 v;
#pragma unroll
        for (int reg = 0; reg < 4; ++reg) {
            const int idx = 16 * e + l16 - quad * 4 - reg + 15;   // in [0,62]
            v[reg] = (_Float16)(rl[idx * 8 + h] * LOG2E);
        }
        *(f16x4*)(tabh + (((size_t)(h * 63 + dy31) * 3 + e) << 8) + lane * 4) = v;
    }
}

// ---------------------------------------------------------------------------
// QKV GEMM, balanced + software-pipelined: grid (256, 3) = 768 blocks (3/CU).
// Block = 32 act-rows x full N=256, one matrix z in {Q, K, V}.
// A staged once to LDS; B streamed from frag-packed wtp with NEXT-kk register
// prefetch (4 wtp b128 + 2 LDS b128 in flight across each MFMA group).
// Q/K: swapped MFMA (D[m=hd][n=act]); V: normal. Epilogue: LDS transpose
// round-trip -> fragment-packed qs/ks/vs.
// ---------------------------------------------------------------------------
__global__ __launch_bounds__(256)
void gemm_qkv_kernel(const float* __restrict__ in_q, const float* __restrict__ in_kv,
                     const _Float16* __restrict__ wtp,
                     const float* __restrict__ bq, const float* __restrict__ bk,
                     const float* __restrict__ bv,
                     _Float16* __restrict__ qs, _Float16* __restrict__ ks,
                     _Float16* __restrict__ vs) {
    __shared__ __align__(16) _Float16 Lds[256 * 40];   // 20.5 KB, reused 3 ways
    const int tid  = threadIdx.x;
    const int w    = tid >> 6;
    const int lane = tid & 63;
    const int quad = lane >> 4;
    const int l16  = lane & 15;
    const int mt = blockIdx.x;         // 32-row tile, 0..255
    const int z  = blockIdx.y;         // 0=Q, 1=K, 2=V
    const int m0 = mt * 32;
    const int b  = mt >> 5, t = mt & 31;

    // stage A tile 32x256 fp32 -> fp16 (stride 264)
    {
        const int r  = tid >> 3;
        const int c4 = (tid & 7) * 4;
        const float* src = (z ? in_kv : in_q) + (size_t)(m0 + r) * 256 + c4;
        _Float16* dst = Lds + r * 264 + c4;
#pragma unroll
        for (int g = 0; g < 8; ++g) {
            f32x4 v = *(const f32x4*)(src + g * 32);
            f16x4 o;
#pragma unroll
            for (int j = 0; j < 4; ++j) o[j] = (_Float16)v[j];
            *(f16x4*)(dst + g * 32) = o;
        }
    }
    __syncthreads();

    f32x4 acc[2][4];
#pragma unroll
    for (int jj = 0; jj < 2; ++jj)
#pragma unroll
        for (int i = 0; i < 4; ++i) acc[jj][i] = (f32x4){0.f, 0.f, 0.f, 0.f};

    const _Float16* wbase = wtp + (((size_t)(z * 16 + w * 4) * 8) << 9) + lane * 8;
    // prologue: kk=0 operands
    f16x8 wc[4], wn[4];
#pragma unroll
    for (int i = 0; i < 4; ++i) wc[i] = *(const f16x8*)(wbase + ((i * 8) << 9));
    f16x8 a0 = *(const f16x8*)(Lds + l16 * 264 + quad * 8);
    f16x8 a1 = *(const f16x8*)(Lds + (16 + l16) * 264 + quad * 8);

#pragma unroll
    for (int kk = 0; kk < 8; ++kk) {
        f16x8 a0n, a1n;
        if (kk < 7) {   // prefetch next-kk operands before current MFMAs
#pragma unroll
            for (int i = 0; i < 4; ++i)
                wn[i] = *(const f16x8*)(wbase + ((i * 8 + kk + 1) << 9));
            const int k8 = (kk + 1) * 32 + quad * 8;
            a0n = *(const f16x8*)(Lds + l16 * 264 + k8);
            a1n = *(const f16x8*)(Lds + (16 + l16) * 264 + k8);
        }
#pragma unroll
        for (int i = 0; i < 4; ++i) {
            if (z < 2) {
                acc[0][i] = __builtin_amdgcn_mfma_f32_16x16x32_f16(wc[i], a0, acc[0][i], 0, 0, 0);
                acc[1][i] = __builtin_amdgcn_mfma_f32_16x16x32_f16(wc[i], a1, acc[1][i], 0, 0, 0);
            } else {
                acc[0][i] = __builtin_amdgcn_mfma_f32_16x16x32_f16(a0, wc[i], acc[0][i], 0, 0, 0);
                acc[1][i] = __builtin_amdgcn_mfma_f32_16x16x32_f16(a1, wc[i], acc[1][i], 0, 0, 0);
            }
        }
        if (kk < 7) {
#pragma unroll
            for (int i = 0; i < 4; ++i) wc[i] = wn[i];
            a0 = a0n; a1 = a1n;
        }
    }
    __syncthreads();   // LDS reuse

    if (z < 2) {
        // Ta[act 32][hd 256] stride 264: D^T with bias + scale
        const float* bias = z ? bk : bq;
        const float  sc   = z ? 1.0f : QSCALE_LOG2E;
#pragma unroll
        for (int i = 0; i < 4; ++i) {
            f32x4 b4 = *(const f32x4*)(bias + (w * 4 + i) * 16 + quad * 4);
#pragma unroll
            for (int jj = 0; jj < 2; ++jj) {
                f16x4 pk;
#pragma unroll
                for (int r = 0; r < 4; ++r) pk[r] = (_Float16)((acc[jj][i][r] + b4[r]) * sc);
                *(f16x4*)(Lds + (jj * 16 + l16) * 264 + (w * 4 + i) * 16 + quad * 4) = pk;
            }
        }
        __syncthreads();
        _Float16* dst = z ? ks : qs;
#pragma unroll
        for (int c = 0; c < 4; ++c) {
            const int sg = w * 4 + c;          // 0..15
            const int sub = sg >> 3, h = sg & 7;
            f16x8 v = *(const f16x8*)(Lds + (sub * 16 + l16) * 264 + h * 32 + quad * 8);
            *(f16x8*)(dst + (((size_t)((b * 8 + h) * 32 + t) * 2 + sub) << 9) + lane * 8) = v;
        }
    } else {
        // Tb[hd 256][key 32] stride 40: V^T with bias
#pragma unroll
        for (int i = 0; i < 4; ++i) {
            const float bvv = bv[(w * 4 + i) * 16 + l16];
#pragma unroll
            for (int jj = 0; jj < 2; ++jj) {
                f16x4 pk;
#pragma unroll
                for (int r = 0; r < 4; ++r) pk[r] = (_Float16)(acc[jj][i][r] + bvv);
                *(f16x4*)(Lds + ((w * 4 + i) * 16 + l16) * 40 + jj * 16 + quad * 4) = pk;
            }
        }
        __syncthreads();
#pragma unroll
        for (int c = 0; c < 4; ++c) {
            const int sg = w * 4 + c;
            const int sub = sg >> 3, h = sg & 7;
            f16x8 v = *(const f16x8*)(Lds + (h * 32 + sub * 16 + l16) * 40 + quad * 8);
            *(f16x8*)(vs + (((size_t)((b * 8 + h) * 32 + t) * 2 + sub) << 9) + lane * 8) = v;
        }
    }
}

// ---------------------------------------------------------------------------
// Output GEMM: zero-LDS, zero-barrier. A = xs (frag-packed by attn),
// B = wtp[mat 3] frag-packed stream. 512 blocks.
// ---------------------------------------------------------------------------
__global__ __launch_bounds__(256)
void gemm_out_kernel(const _Float16* __restrict__ xs, const _Float16* __restrict__ wtp,
                     const float* __restrict__ bo, float* __restrict__ out) {
    const int tid  = threadIdx.x;
    const int w    = tid >> 6;
    const int lane = tid & 63;
    const int quad = lane >> 4;
    const int l16  = lane & 15;
    const int bx = blockIdx.x, by = blockIdx.y;
    const int mt0  = bx * 4 + (w & 1) * 2;
    const int n16a = by * 4 + (w >> 1) * 2;

    f32x4 acc[2][2];
#pragma unroll
    for (int i = 0; i < 2; ++i)
#pragma unroll
        for (int j = 0; j < 2; ++j) acc[i][j] = (f32x4){0.f, 0.f, 0.f, 0.f};

#pragma unroll
    for (int kk = 0; kk < 8; ++kk) {
        f16x8 a0 = *(const f16x8*)(xs + (((size_t)(mt0 + 0) * 8 + kk) << 9) + lane * 8);
        f16x8 a1 = *(const f16x8*)(xs + (((size_t)(mt0 + 1) * 8 + kk) << 9) + lane * 8);
        f16x8 b0 = *(const f16x8*)(wtp + (((size_t)(48 + n16a + 0) * 8 + kk) << 9) + lane * 8);
        f16x8 b1 = *(const f16x8*)(wtp + (((size_t)(48 + n16a + 1) * 8 + kk) << 9) + lane * 8);
        acc[0][0] = __builtin_amdgcn_mfma_f32_16x16x32_f16(a0, b0, acc[0][0], 0, 0, 0);
        acc[0][1] = __builtin_amdgcn_mfma_f32_16x16x32_f16(a0, b1, acc[0][1], 0, 0, 0);
        acc[1][0] = __builtin_amdgcn_mfma_f32_16x16x32_f16(a1, b0, acc[1][0], 0, 0, 0);
        acc[1][1] = __builtin_amdgcn_mfma_f32_16x16x32_f16(a1, b1, acc[1][1], 0, 0, 0);
    }

#pragma unroll
    for (int i = 0; i < 2; ++i) {
        const int col = (n16a + i) * 16 + l16;
        const float bvv = bo[col];
#pragma unroll
        for (int jj = 0; jj < 2; ++jj) {
#pragma unroll
            for (int r = 0; r < 4; ++r) {
                const int row = (mt0 + jj) * 16 + quad * 4 + r;
                out[(size_t)row * 256 + col] = acc[jj][i][r] + bvv;
            }
        }
    }
}

// ---------------------------------------------------------------------------
// Flash attention: 1024 blocks (XCD-swizzled: bh 0..63, qc 0..15), 4 waves,
// wave = 16 q-rows, 32 KV tiles, ZERO barriers, fixed-max softmax.
// 4 blocks/CU = 16 waves/CU. Packed streams, fp16 tab C-init, ones-MFMA
// row sums, wave-private P round-trip, packed-xs epilogue.
// ---------------------------------------------------------------------------
__global__ __launch_bounds__(256)
void attn_kernel(const _Float16* __restrict__ qs, const _Float16* __restrict__ ks,
                 const _Float16* __restrict__ vs, const _Float16* __restrict__ tabh,
                 _Float16* __restrict__ xs) {
    __shared__ __align__(16) _Float16 Ps[4][16][40];   // 5.1 KB

    const int tid  = threadIdx.x;
    const int w    = tid >> 6;
    const int lane = tid & 63;
    const int quad = lane >> 4;
    const int l16  = lane & 15;

    const int n     = blockIdx.x;
    const int xcd   = n & 7;
    const int local = n >> 3;              // 0..127
    const int bh    = xcd * 8 + (local & 7);
    const int qc    = local >> 3;          // 0..15
    const int b = bh >> 3, h = bh & 7;
    const int qrow_base = qc * 64 + w * 16;
    const int yq  = qrow_base >> 5;        // 32-q y-tile (= qc*2 + (w>>1))
    const int sub = (qrow_base >> 4) & 1;  // = w & 1
    const int e0  = sub + 1;               // tab slice for keys 0-15
    const int e1  = sub;                   // tab slice for keys 16-31

    // Q B-frag from packed qs
    const f16x8 qf =
        *(const f16x8*)(qs + (((size_t)(bh * 32 + yq) * 2 + sub) << 9) + lane * 8);
    const _Float16* kp = ks + (((size_t)bh * 64) << 9) + lane * 8;   // +kt*1024
    const _Float16* vp = vs + (((size_t)bh * 64) << 9) + lane * 8;
    const _Float16* tb = tabh + (((size_t)h * 189) << 8) + lane * 4;

    f16x8 ones;
#pragma unroll
    for (int j = 0; j < 8; ++j) ones[j] = (_Float16)1.0f;

    f32x4 o0 = {0.f,0.f,0.f,0.f}, o1 = {0.f,0.f,0.f,0.f}, ol = {0.f,0.f,0.f,0.f};

    // prologue: tile-0 operands
    f16x8 kf0 = *(const f16x8*)(kp);
    f16x8 kf1 = *(const f16x8*)(kp + 512);
    f16x8 vf0 = *(const f16x8*)(vp);
    f16x8 vf1 = *(const f16x8*)(vp + 512);
    f32x4 c0, c1;
    {
        f16x4 t0 = *(const f16x4*)(tb + (((yq + 31) * 3 + e0) << 8));
        f16x4 t1 = *(const f16x4*)(tb + (((yq + 31) * 3 + e1) << 8));
#pragma unroll
        for (int r = 0; r < 4; ++r) { c0[r] = (float)t0[r]; c1[r] = (float)t1[r]; }
    }

    for (int kt = 0; kt < 32; ++kt) {
        const bool more = (kt < 31);
        f16x8 nk0, nk1, nv0, nv1;
        f16x4 nt0, nt1;
        if (more) {   // prefetch next tile
            const _Float16* kq = kp + (kt + 1) * 1024;
            nk0 = *(const f16x8*)(kq);
            nk1 = *(const f16x8*)(kq + 512);
            const _Float16* vq = vp + (kt + 1) * 1024;
            nv0 = *(const f16x8*)(vq);
            nv1 = *(const f16x8*)(vq + 512);
            const int d = (yq + 30 - kt) * 3;
            nt0 = *(const f16x4*)(tb + ((d + e0) << 8));
            nt1 = *(const f16x4*)(tb + ((d + e1) << 8));
        }

        // S^T = K.Q^T + bias (C-init); rows = keys, cols = q
        f32x4 s0 = __builtin_amdgcn_mfma_f32_16x16x32_f16(kf0, qf, c0, 0, 0, 0);
        f32x4 s1 = __builtin_amdgcn_mfma_f32_16x16x32_f16(kf1, qf, c1, 0, 0, 0);

        f16x4 p;
#pragma unroll
        for (int r = 0; r < 4; ++r) p[r] = (_Float16)__builtin_amdgcn_exp2f(s0[r]);
        *(f16x4*)(&Ps[w][l16][quad * 4]) = p;
#pragma unroll
        for (int r = 0; r < 4; ++r) p[r] = (_Float16)__builtin_amdgcn_exp2f(s1[r]);
        *(f16x4*)(&Ps[w][l16][16 + quad * 4]) = p;

        const f16x8 pf = *(const f16x8*)(&Ps[w][l16][quad * 8]);
        o0 = __builtin_amdgcn_mfma_f32_16x16x32_f16(vf0, pf, o0, 0, 0, 0);
        o1 = __builtin_amdgcn_mfma_f32_16x16x32_f16(vf1, pf, o1, 0, 0, 0);
        ol = __builtin_amdgcn_mfma_f32_16x16x32_f16(ones, pf, ol, 0, 0, 0);

        if (more) {
            kf0 = nk0; kf1 = nk1; vf0 = nv0; vf1 = nv1;
#pragma unroll
            for (int r = 0; r < 4; ++r) { c0[r] = (float)nt0[r]; c1[r] = (float)nt1[r]; }
        }
    }

    // epilogue: normalize, wave-private LDS transpose, packed xs store
    const float inv = __builtin_amdgcn_rcpf(ol[0]);
    f16x4 u, v;
#pragma unroll
    for (int r = 0; r < 4; ++r) {
        u[r] = (_Float16)(o0[r] * inv);
        v[r] = (_Float16)(o1[r] * inv);
    }
    *(f16x4*)(&Ps[w][l16][quad * 4]) = u;        // x[q=l16][hd=quad*4+r]
    *(f16x4*)(&Ps[w][l16][16 + quad * 4]) = v;   // x[q=l16][hd=16+quad*4+r]
    const f16x8 af = *(const f16x8*)(&Ps[w][l16][quad * 8]);
    const int mtile = b * 64 + qc * 4 + w;
    *(f16x8*)(xs + (((size_t)mtile * 8 + h) << 9) + lane * 8) = af;
}

// ---------------------------------------------------------------------------
extern "C" void kernel_launch(void* const* d_in, const int* in_sizes, int n_in,
                              void* d_out, int out_size, void* d_ws, size_t ws_size,
                              hipStream_t stream) {
    const float* in_q  = (const float*)d_in[0];
    const float* in_kv = (const float*)d_in[1];
    const float* Wq    = (const float*)d_in[2];
    const float* bq    = (const float*)d_in[3];
    const float* Wk    = (const float*)d_in[4];
    const float* bk    = (const float*)d_in[5];
    const float* Wv    = (const float*)d_in[6];
    const float* bv    = (const float*)d_in[7];
    const float* rel   = (const float*)d_in[8];
    const float* Wo    = (const float*)d_in[9];
    const float* bo    = (const float*)d_in[10];
    float* out = (float*)d_out;

    char* wsb = (char*)d_ws;
    _Float16* qs   = (_Float16*)(wsb);                         // 4 MB packed Q
    _Float16* ks   = (_Float16*)(wsb + (size_t)4  * 1048576);  // 4 MB packed K
    _Float16* vs   = (_Float16*)(wsb + (size_t)8  * 1048576);  // 4 MB packed V^T
    _Float16* xs   = (_Float16*)(wsb + (size_t)12 * 1048576);  // 4 MB packed X
    _Float16* wtp  = (_Float16*)(wsb + (size_t)16 * 1048576);  // 512 KB packed W
    _Float16* tabh = (_Float16*)(wsb + (size_t)17 * 1048576);  // 774 KB fp16 tab

    const dim3 blk(256);

    prep_kernel<<<dim3(95), blk, 0, stream>>>(Wq, Wk, Wv, Wo, rel, wtp, tabh);
    gemm_qkv_kernel<<<dim3(256, 3), blk, 0, stream>>>(
        in_q, in_kv, wtp, bq, bk, bv, qs, ks, vs);
    attn_kernel<<<dim3(1024), blk, 0, stream>>>(qs, ks, vs, tabh, xs);
    gemm_out_kernel<<<dim3(128, 4), blk, 0, stream>>>(xs, wtp, bo, out);
}

// Round 10
// 129.223 us; speedup vs baseline: 1.0161x; 1.0161x over previous
//
#include <hip/hip_runtime.h>

// Problem constants
#define B_SZ   8
#define S_LEN  1024
#define D_MOD  256
#define NHEADS 8
#define LOG2E  1.4426950408889634f
#define QSCALE_LOG2E 0.2550352766751165f   // (1/sqrt(32)) * log2(e)

typedef _Float16 f16x8 __attribute__((ext_vector_type(8)));
typedef _Float16 f16x4 __attribute__((ext_vector_type(4)));
typedef float    f32x4 __attribute__((ext_vector_type(4)));

// ---------------------------------------------------------------------------
// prep: blocks 0..31  : pack 4 fp32 W mats -> fragment-ordered fp16 wtp.
//        wtp[((mat*16+n16)*8+kk)*512 + lane*8 + j]
//          = W[kk*32 + (lane>>4)*8 + j][n16*16 + (lane&15)]
//       blocks 32..94 : fp16 bias C-init table
//        tabh[((h*63+dy31)*3+e)*256 + lane*4 + r]
//          = rel[(dy31*63 + 16e + l16 - quad*4 - r + 15)*8 + h] * LOG2E
// ---------------------------------------------------------------------------
__global__ __launch_bounds__(256)
void prep_kernel(const float* __restrict__ Wq, const float* __restrict__ Wk,
                 const float* __restrict__ Wv, const float* __restrict__ Wo,
                 const float* __restrict__ rel,
                 _Float16* __restrict__ wtp, _Float16* __restrict__ tabh) {
    if (blockIdx.x < 32) {
        __shared__ _Float16 Wl[32 * 264];
        const int mi = blockIdx.x >> 3;
        const int k0 = (blockIdx.x & 7) << 5;
        const float* W = (mi == 0) ? Wq : (mi == 1) ? Wk : (mi == 2) ? Wv : Wo;
        {
            const int r  = threadIdx.x >> 3;
            const int c4 = (threadIdx.x & 7) * 4;
            const float* src = W + (size_t)(k0 + r) * 256 + c4;
#pragma unroll
            for (int g = 0; g < 8; ++g) {
                f32x4 v = *(const f32x4*)(src + g * 32);
                f16x4 o;
#pragma unroll
                for (int j = 0; j < 4; ++j) o[j] = (_Float16)v[j];
                *(f16x4*)(&Wl[r * 264 + c4 + g * 32]) = o;
            }
        }
        __syncthreads();
        const int n16 = threadIdx.x >> 4;
        const int l16 = threadIdx.x & 15;
        const int kk  = k0 >> 5;
#pragma unroll
        for (int quad = 0; quad < 4; ++quad) {
            f16x8 v;
#pragma unroll
            for (int j = 0; j < 8; ++j) v[j] = Wl[(quad * 8 + j) * 264 + n16 * 16 + l16];
            *(f16x8*)(wtp + (((size_t)(mi * 16 + n16) * 8 + kk) << 9) + (quad * 16 + l16) * 8) = v;
        }
        return;
    }
    __shared__ float rl[63 * 8];
    const int dy31 = blockIdx.x - 32;
    for (int f = threadIdx.x; f < 504; f += 256) rl[f] = rel[(size_t)dy31 * 504 + f];
    __syncthreads();
    const int h  = threadIdx.x >> 5;
    const int r5 = threadIdx.x & 31;
#pragma unroll
    for (int c = 0; c < 6; ++c) {
        const int oi   = r5 * 6 + c;       // 0..191
        const int e    = oi >> 6;
        const int lane = oi & 63;
        const int quad = lane >> 4, l16 = lane & 15;
        f16x4 v;
#pragma unroll
        for (int reg = 0; reg < 4; ++reg) {
            const int idx = 16 * e + l16 - quad * 4 - reg + 15;   // in [0,62]
            v[reg] = (_Float16)(rl[idx * 8 + h] * LOG2E);
        }
        *(f16x4*)(tabh + (((size_t)(h * 63 + dy31) * 3 + e) << 8) + lane * 4) = v;
    }
}

// ---------------------------------------------------------------------------
// QKV GEMM, balanced: grid (256, 3) = 768 equal blocks (3/CU).
// Block = 32 act-rows x full N=256, one matrix z in {Q, K, V}.
// A staged once to LDS (coalesced); B streamed from frag-packed wtp.
// Q/K use swapped MFMA operands (D[m=hd][n=act]); V normal (D[m=key][n=hd]).
// Epilogue: LDS transpose round-trip -> fragment-packed qs/ks/vs.
// ---------------------------------------------------------------------------
__global__ __launch_bounds__(256)
void gemm_qkv_kernel(const float* __restrict__ in_q, const float* __restrict__ in_kv,
                     const _Float16* __restrict__ wtp,
                     const float* __restrict__ bq, const float* __restrict__ bk,
                     const float* __restrict__ bv,
                     _Float16* __restrict__ qs, _Float16* __restrict__ ks,
                     _Float16* __restrict__ vs) {
    __shared__ __align__(16) _Float16 Lds[256 * 40];   // 20.5 KB, reused 3 ways
    const int tid  = threadIdx.x;
    const int w    = tid >> 6;
    const int lane = tid & 63;
    const int quad = lane >> 4;
    const int l16  = lane & 15;
    const int mt = blockIdx.x;         // 32-row tile, 0..255
    const int z  = blockIdx.y;         // 0=Q, 1=K, 2=V
    const int m0 = mt * 32;
    const int b  = mt >> 5, t = mt & 31;

    // stage A tile 32x256 fp32 -> fp16 (stride 264)
    {
        const int r  = tid >> 3;
        const int c4 = (tid & 7) * 4;
        const float* src = (z ? in_kv : in_q) + (size_t)(m0 + r) * 256 + c4;
        _Float16* dst = Lds + r * 264 + c4;
#pragma unroll
        for (int g = 0; g < 8; ++g) {
            f32x4 v = *(const f32x4*)(src + g * 32);
            f16x4 o;
#pragma unroll
            for (int j = 0; j < 4; ++j) o[j] = (_Float16)v[j];
            *(f16x4*)(dst + g * 32) = o;
        }
    }
    __syncthreads();

    f32x4 acc[2][4];
#pragma unroll
    for (int jj = 0; jj < 2; ++jj)
#pragma unroll
        for (int i = 0; i < 4; ++i) acc[jj][i] = (f32x4){0.f, 0.f, 0.f, 0.f};

#pragma unroll
    for (int kk = 0; kk < 8; ++kk) {
        const int k8 = kk * 32 + quad * 8;
        f16x8 a0 = *(const f16x8*)(Lds + l16 * 264 + k8);
        f16x8 a1 = *(const f16x8*)(Lds + (16 + l16) * 264 + k8);
#pragma unroll
        for (int i = 0; i < 4; ++i) {
            f16x8 wv = *(const f16x8*)(wtp + (((size_t)(z * 16 + w * 4 + i) * 8 + kk) << 9) + lane * 8);
            if (z < 2) {
                acc[0][i] = __builtin_amdgcn_mfma_f32_16x16x32_f16(wv, a0, acc[0][i], 0, 0, 0);
                acc[1][i] = __builtin_amdgcn_mfma_f32_16x16x32_f16(wv, a1, acc[1][i], 0, 0, 0);
            } else {
                acc[0][i] = __builtin_amdgcn_mfma_f32_16x16x32_f16(a0, wv, acc[0][i], 0, 0, 0);
                acc[1][i] = __builtin_amdgcn_mfma_f32_16x16x32_f16(a1, wv, acc[1][i], 0, 0, 0);
            }
        }
    }
    __syncthreads();   // LDS reuse

    if (z < 2) {
        // Ta[act 32][hd 256] stride 264: D^T with bias + scale
        const float* bias = z ? bk : bq;
        const float  sc   = z ? 1.0f : QSCALE_LOG2E;
#pragma unroll
        for (int i = 0; i < 4; ++i) {
            f32x4 b4 = *(const f32x4*)(bias + (w * 4 + i) * 16 + quad * 4);
#pragma unroll
            for (int jj = 0; jj < 2; ++jj) {
                f16x4 pk;
#pragma unroll
                for (int r = 0; r < 4; ++r) pk[r] = (_Float16)((acc[jj][i][r] + b4[r]) * sc);
                *(f16x4*)(Lds + (jj * 16 + l16) * 264 + (w * 4 + i) * 16 + quad * 4) = pk;
            }
        }
        __syncthreads();
        _Float16* dst = z ? ks : qs;
#pragma unroll
        for (int c = 0; c < 4; ++c) {
            const int sg = w * 4 + c;          // 0..15
            const int sub = sg >> 3, h = sg & 7;
            f16x8 v = *(const f16x8*)(Lds + (sub * 16 + l16) * 264 + h * 32 + quad * 8);
            *(f16x8*)(dst + (((size_t)((b * 8 + h) * 32 + t) * 2 + sub) << 9) + lane * 8) = v;
        }
    } else {
        // Tb[hd 256][key 32] stride 40: V^T with bias
#pragma unroll
        for (int i = 0; i < 4; ++i) {
            const float bvv = bv[(w * 4 + i) * 16 + l16];
#pragma unroll
            for (int jj = 0; jj < 2; ++jj) {
                f16x4 pk;
#pragma unroll
                for (int r = 0; r < 4; ++r) pk[r] = (_Float16)(acc[jj][i][r] + bvv);
                *(f16x4*)(Lds + ((w * 4 + i) * 16 + l16) * 40 + jj * 16 + quad * 4) = pk;
            }
        }
        __syncthreads();
#pragma unroll
        for (int c = 0; c < 4; ++c) {
            const int sg = w * 4 + c;
            const int sub = sg >> 3, h = sg & 7;
            f16x8 v = *(const f16x8*)(Lds + (h * 32 + sub * 16 + l16) * 40 + quad * 8);
            *(f16x8*)(vs + (((size_t)((b * 8 + h) * 32 + t) * 2 + sub) << 9) + lane * 8) = v;
        }
    }
}

// ---------------------------------------------------------------------------
// Output GEMM: zero-LDS, zero-barrier. A = xs (frag-packed by attn),
// B = wtp[mat 3] frag-packed stream. 512 blocks.
// ---------------------------------------------------------------------------
__global__ __launch_bounds__(256)
void gemm_out_kernel(const _Float16* __restrict__ xs, const _Float16* __restrict__ wtp,
                     const float* __restrict__ bo, float* __restrict__ out) {
    const int tid  = threadIdx.x;
    const int w    = tid >> 6;
    const int lane = tid & 63;
    const int quad = lane >> 4;
    const int l16  = lane & 15;
    const int bx = blockIdx.x, by = blockIdx.y;
    const int mt0  = bx * 4 + (w & 1) * 2;
    const int n16a = by * 4 + (w >> 1) * 2;

    f32x4 acc[2][2];
#pragma unroll
    for (int i = 0; i < 2; ++i)
#pragma unroll
        for (int j = 0; j < 2; ++j) acc[i][j] = (f32x4){0.f, 0.f, 0.f, 0.f};

#pragma unroll
    for (int kk = 0; kk < 8; ++kk) {
        f16x8 a0 = *(const f16x8*)(xs + (((size_t)(mt0 + 0) * 8 + kk) << 9) + lane * 8);
        f16x8 a1 = *(const f16x8*)(xs + (((size_t)(mt0 + 1) * 8 + kk) << 9) + lane * 8);
        f16x8 b0 = *(const f16x8*)(wtp + (((size_t)(48 + n16a + 0) * 8 + kk) << 9) + lane * 8);
        f16x8 b1 = *(const f16x8*)(wtp + (((size_t)(48 + n16a + 1) * 8 + kk) << 9) + lane * 8);
        acc[0][0] = __builtin_amdgcn_mfma_f32_16x16x32_f16(a0, b0, acc[0][0], 0, 0, 0);
        acc[0][1] = __builtin_amdgcn_mfma_f32_16x16x32_f16(a0, b1, acc[0][1], 0, 0, 0);
        acc[1][0] = __builtin_amdgcn_mfma_f32_16x16x32_f16(a1, b0, acc[1][0], 0, 0, 0);
        acc[1][1] = __builtin_amdgcn_mfma_f32_16x16x32_f16(a1, b1, acc[1][1], 0, 0, 0);
    }

#pragma unroll
    for (int i = 0; i < 2; ++i) {
        const int col = (n16a + i) * 16 + l16;
        const float bvv = bo[col];
#pragma unroll
        for (int jj = 0; jj < 2; ++jj) {
#pragma unroll
            for (int r = 0; r < 4; ++r) {
                const int row = (mt0 + jj) * 16 + quad * 4 + r;
                out[(size_t)row * 256 + col] = acc[jj][i][r] + bvv;
            }
        }
    }
}

// ---------------------------------------------------------------------------
// Flash attention (R8 core + LDS tab): 512 blocks (XCD-swizzled: bh, qc 0..7),
// 4 waves, wave = 32 q-rows, 32 KV tiles, fixed-max softmax.
// Bias tab rows [qc*4, qc*4+34] staged to LDS ONCE (52.5 KB, one barrier at
// start); per-iter C-init = 3 conflict-free ds_read_b64 (VMEM 6 -> 4 per
// wave-iter). K-loop itself remains barrier-free. Packed streams, ones-MFMA
// row sums, wave-private P round-trip, packed-xs epilogue.
// ---------------------------------------------------------------------------
__global__ __launch_bounds__(256)
void attn_kernel(const _Float16* __restrict__ qs, const _Float16* __restrict__ ks,
                 const _Float16* __restrict__ vs, const _Float16* __restrict__ tabh,
                 _Float16* __restrict__ xs) {
    __shared__ __align__(16) _Float16 Ps[4][32][40];     // 10.25 KB
    __shared__ __align__(16) _Float16 TabL[35 * 768];    // 52.5 KB

    const int tid  = threadIdx.x;
    const int w    = tid >> 6;
    const int lane = tid & 63;
    const int quad = lane >> 4;
    const int l16  = lane & 15;

    const int n     = blockIdx.x;
    const int xcd   = n & 7;
    const int local = n >> 3;
    const int bh    = xcd * 8 + (local & 7);
    const int qc    = local >> 3;          // 0..7
    const int b = bh >> 3, h = bh & 7;
    const int yq = qc * 4 + w;             // q y-tile 0..31

    // stage tab rows dy31 in [qc*4, qc*4+34] for head h (contiguous copy)
    {
        const _Float16* gsrc = tabh + ((size_t)(h * 63 + qc * 4)) * 768;
        for (int i = tid * 8; i < 35 * 768; i += 2048)
            *(f16x8*)(&TabL[i]) = *(const f16x8*)(gsrc + i);
    }

    const _Float16* qp = qs + (((size_t)(bh * 32 + yq) * 2) << 9) + lane * 8;
    const f16x8 qf0 = *(const f16x8*)(qp);
    const f16x8 qf1 = *(const f16x8*)(qp + 512);
    const _Float16* kp = ks + (((size_t)bh * 64) << 9) + lane * 8;   // +kt*1024
    const _Float16* vp = vs + (((size_t)bh * 64) << 9) + lane * 8;

    f16x8 ones;
#pragma unroll
    for (int j = 0; j < 8; ++j) ones[j] = (_Float16)1.0f;

    f32x4 o00 = {0.f,0.f,0.f,0.f}, o01 = {0.f,0.f,0.f,0.f};
    f32x4 o10 = {0.f,0.f,0.f,0.f}, o11 = {0.f,0.f,0.f,0.f};
    f32x4 ol0 = {0.f,0.f,0.f,0.f}, ol1 = {0.f,0.f,0.f,0.f};

    f16x8 kf0 = *(const f16x8*)(kp);
    f16x8 kf1 = *(const f16x8*)(kp + 512);
    f16x8 vf0 = *(const f16x8*)(vp);
    f16x8 vf1 = *(const f16x8*)(vp + 512);

    __syncthreads();   // tab staged (placed after global prefetches)

    for (int kt = 0; kt < 32; ++kt) {
        const bool more = (kt < 31);
        f16x8 nk0, nk1, nv0, nv1;
        if (more) {
            const _Float16* kq = kp + (kt + 1) * 1024;
            nk0 = *(const f16x8*)(kq);
            nk1 = *(const f16x8*)(kq + 512);
            const _Float16* vq = vp + (kt + 1) * 1024;
            nv0 = *(const f16x8*)(vq);
            nv1 = *(const f16x8*)(vq + 512);
        }

        // bias C-init from LDS: dyLocal = w + 31 - kt (in [0,34])
        f32x4 c0, c1, c2;
        {
            const _Float16* tl = &TabL[(w + 31 - kt) * 768 + lane * 4];
            f16x4 t0 = *(const f16x4*)(tl);         // e=0
            f16x4 t1 = *(const f16x4*)(tl + 256);   // e=1
            f16x4 t2 = *(const f16x4*)(tl + 512);   // e=2
#pragma unroll
            for (int r = 0; r < 4; ++r) {
                c0[r] = (float)t0[r]; c1[r] = (float)t1[r]; c2[r] = (float)t2[r];
            }
        }

        // S^T = K.Q^T + bias (C-init); rows=keys, cols=q
        f32x4 s00 = __builtin_amdgcn_mfma_f32_16x16x32_f16(kf0, qf0, c1, 0, 0, 0);
        f32x4 s01 = __builtin_amdgcn_mfma_f32_16x16x32_f16(kf1, qf0, c0, 0, 0, 0);
        f32x4 s10 = __builtin_amdgcn_mfma_f32_16x16x32_f16(kf0, qf1, c2, 0, 0, 0);
        f32x4 s11 = __builtin_amdgcn_mfma_f32_16x16x32_f16(kf1, qf1, c1, 0, 0, 0);

        f16x4 p;
#pragma unroll
        for (int r = 0; r < 4; ++r) p[r] = (_Float16)__builtin_amdgcn_exp2f(s00[r]);
        *(f16x4*)(&Ps[w][l16][quad * 4]) = p;
#pragma unroll
        for (int r = 0; r < 4; ++r) p[r] = (_Float16)__builtin_amdgcn_exp2f(s01[r]);
        *(f16x4*)(&Ps[w][l16][16 + quad * 4]) = p;
#pragma unroll
        for (int r = 0; r < 4; ++r) p[r] = (_Float16)__builtin_amdgcn_exp2f(s10[r]);
        *(f16x4*)(&Ps[w][16 + l16][quad * 4]) = p;
#pragma unroll
        for (int r = 0; r < 4; ++r) p[r] = (_Float16)__builtin_amdgcn_exp2f(s11[r]);
        *(f16x4*)(&Ps[w][16 + l16][16 + quad * 4]) = p;

        const f16x8 pf0 = *(const f16x8*)(&Ps[w][l16][quad * 8]);
        const f16x8 pf1 = *(const f16x8*)(&Ps[w][16 + l16][quad * 8]);
        o00 = __builtin_amdgcn_mfma_f32_16x16x32_f16(vf0, pf0, o00, 0, 0, 0);
        o01 = __builtin_amdgcn_mfma_f32_16x16x32_f16(vf0, pf1, o01, 0, 0, 0);
        o10 = __builtin_amdgcn_mfma_f32_16x16x32_f16(vf1, pf0, o10, 0, 0, 0);
        o11 = __builtin_amdgcn_mfma_f32_16x16x32_f16(vf1, pf1, o11, 0, 0, 0);
        ol0 = __builtin_amdgcn_mfma_f32_16x16x32_f16(ones, pf0, ol0, 0, 0, 0);
        ol1 = __builtin_amdgcn_mfma_f32_16x16x32_f16(ones, pf1, ol1, 0, 0, 0);

        if (more) { kf0 = nk0; kf1 = nk1; vf0 = nv0; vf1 = nv1; }
    }

    // epilogue: normalize, wave-private LDS transpose, packed xs store
#pragma unroll
    for (int qsub = 0; qsub < 2; ++qsub) {
        const f32x4 olo = qsub ? o01 : o00;   // hd 0-15
        const f32x4 ohi = qsub ? o11 : o10;   // hd 16-31
        const f32x4 ll  = qsub ? ol1 : ol0;
        const float inv = __builtin_amdgcn_rcpf(ll[0]);
        f16x4 u, v;
#pragma unroll
        for (int r = 0; r < 4; ++r) {
            u[r] = (_Float16)(olo[r] * inv);
            v[r] = (_Float16)(ohi[r] * inv);
        }
        *(f16x4*)(&Ps[w][qsub * 16 + l16][quad * 4]) = u;
        *(f16x4*)(&Ps[w][qsub * 16 + l16][16 + quad * 4]) = v;
    }
#pragma unroll
    for (int qsub = 0; qsub < 2; ++qsub) {
        f16x8 af = *(const f16x8*)(&Ps[w][qsub * 16 + l16][quad * 8]);
        const int mtile = b * 64 + qc * 8 + w * 2 + qsub;
        *(f16x8*)(xs + (((size_t)mtile * 8 + h) << 9) + lane * 8) = af;
    }
}

// ---------------------------------------------------------------------------
extern "C" void kernel_launch(void* const* d_in, const int* in_sizes, int n_in,
                              void* d_out, int out_size, void* d_ws, size_t ws_size,
                              hipStream_t stream) {
    const float* in_q  = (const float*)d_in[0];
    const float* in_kv = (const float*)d_in[1];
    const float* Wq    = (const float*)d_in[2];
    const float* bq    = (const float*)d_in[3];
    const float* Wk    = (const float*)d_in[4];
    const float* bk    = (const float*)d_in[5];
    const float* Wv    = (const float*)d_in[6];
    const float* bv    = (const float*)d_in[7];
    const float* rel   = (const float*)d_in[8];
    const float* Wo    = (const float*)d_in[9];
    const float* bo    = (const float*)d_in[10];
    float* out = (float*)d_out;

    char* wsb = (char*)d_ws;
    _Float16* qs   = (_Float16*)(wsb);                         // 4 MB packed Q
    _Float16* ks   = (_Float16*)(wsb + (size_t)4  * 1048576);  // 4 MB packed K
    _Float16* vs   = (_Float16*)(wsb + (size_t)8  * 1048576);  // 4 MB packed V^T
    _Float16* xs   = (_Float16*)(wsb + (size_t)12 * 1048576);  // 4 MB packed X
    _Float16* wtp  = (_Float16*)(wsb + (size_t)16 * 1048576);  // 512 KB packed W
    _Float16* tabh = (_Float16*)(wsb + (size_t)17 * 1048576);  // 774 KB fp16 tab

    const dim3 blk(256);

    prep_kernel<<<dim3(95), blk, 0, stream>>>(Wq, Wk, Wv, Wo, rel, wtp, tabh);
    gemm_qkv_kernel<<<dim3(256, 3), blk, 0, stream>>>(
        in_q, in_kv, wtp, bq, bk, bv, qs, ks, vs);
    attn_kernel<<<dim3(512), blk, 0, stream>>>(qs, ks, vs, tabh, xs);
    gemm_out_kernel<<<dim3(128, 4), blk, 0, stream>>>(xs, wtp, bo, out);
}